// Round 6
// baseline (26.376 us; speedup 1.0000x reference)
//
#include <hip/hip_runtime.h>
#include <hip/hip_bf16.h>

typedef __attribute__((ext_vector_type(8))) short bf16x8;
typedef __attribute__((ext_vector_type(4))) float f32x4;
typedef __attribute__((ext_vector_type(16))) float f32x16;

#define NN 1024
#define FF 64
#define OO 128

#define LOG2E    1.4426950408889634f
#define C20L     (20.0f * LOG2E)
#define C10L     (10.0f * LOG2E)
#define NEG_LN2_10 (-0.06931471805599453f)
#define BF1      ((short)0x3F80)        // bf16 1.0

__device__ __forceinline__ short bfh(float f) {
    __hip_bfloat16 h = __float2bfloat16(f);   // RNE
    return *reinterpret_cast<short*>(&h);
}
__device__ __forceinline__ float bf2f(short s) {
    union { unsigned u; float f; } v; v.u = ((unsigned)(unsigned short)s) << 16;
    return v.f;
}

// ============================================================================
// R23: DIAGNOSTIC ROUND. Body = R18 verbatim (best measured: 15.74us).
// Launched TWICE back-to-back (idempotent: overwrites out with identical
// values). Purpose: measure the kernel's TRUE marginal device time K:
//   dur_us(R23) - dur_us(R18) = K + in-graph gap.
// Six rounds of restructuring (2-3x modeled-work changes) all landed within
// ~1us of 15.7 -> hypothesis: dur_us = fixed overhead (~10us, per rocprof.md
// launch-overhead note) + K(~6us). If dur ~ 21-23: hypothesis confirmed,
// kernel is near its practical floor. If dur ~ 30-32: K really is ~15us and
// the pipe model is wrong by 3x -> investigate pairwise trans/VALU for real.
// ============================================================================
__global__ __launch_bounds__(512) void gnn_fused_kernel(
    const float* __restrict__ x, const float* __restrict__ mask,
    const float* __restrict__ A, const float* __restrict__ bias,
    float* __restrict__ out)
{
    __shared__ __align__(16) short  ivec[NN * 8];        // 16 KB: i-side A-slots
    __shared__ __align__(16) bf16x8 jlo[128], jhi[128];  // 4 KB: j-side B-slots
    __shared__ __align__(16) bf16x8 cst;                 // A-slot for lanes>=32
    __shared__ __align__(16) float part_w[2][2][64];     // [tile][ih][j]
    __shared__ __align__(16) float part_t[2][2][64];

    const int tid = threadIdx.x;
    const int w   = tid >> 6;
    const int l   = tid & 63;
    const int l16 = l & 15;
    const int lh  = l >> 4;

    // XCD swizzle: all 8 j-tile blocks of a batch share one XCD (bid%8).
    const int bid = blockIdx.x;
    const int b     = (bid & 7) * 4 + (bid >> 6);
    const int jbase = ((bid >> 3) & 7) * 128;
    const int rowbase_g = b * NN + jbase;
    const float* xb = x + (size_t)b * NN * FF;

    // ---- Phase A (all waves): build split-bf16 slot vectors ----
    // p2[j][i] = vx_i*x_j + vy_i*y_j + u_i + u_j   (log2-domain, = -10L*dist)
    // A(i) k0..7: [vxh,vxl,vxh,vyh,vyl,vyh,uh,ul]  B(j) k0..7: [xh,xh,xl,yh,yh,yl,1,1]
    // lanes>=32 (k8..15): A=[1,1,0..]  B=[ujh,ujl,0..]
    #pragma unroll
    for (int q = 0; q < 2; ++q) {
        int p = tid + q * 512;
        float2 c2 = *(const float2*)(xb + (size_t)p * FF + (FF - 2));
        float vx = C20L * c2.x, vy = C20L * c2.y;
        float r2 = fmaf(c2.x, c2.x, c2.y * c2.y);
        float u  = -C10L * r2;
        short vxh = bfh(vx); short vxl = bfh(vx - bf2f(vxh));
        short vyh = bfh(vy); short vyl = bfh(vy - bf2f(vyh));
        short uh  = bfh(u);  short ul  = bfh(u  - bf2f(uh));
        bf16x8 iv = {vxh, vxl, vxh, vyh, vyl, vyh, uh, ul};
        *(bf16x8*)&ivec[p * 8] = iv;
        unsigned jloc = (unsigned)(p - jbase);
        if (jloc < 128u) {
            short xh = bfh(c2.x); short xl = bfh(c2.x - bf2f(xh));
            short yh = bfh(c2.y); short yl = bfh(c2.y - bf2f(yh));
            jlo[jloc] = (bf16x8){xh, xh, xl, yh, yh, yl, BF1, BF1};
            jhi[jloc] = (bf16x8){uh, ul, 0, 0, 0, 0, 0, 0};
        }
    }
    if (tid == 0) cst = (bf16x8){BF1, BF1, 0, 0, 0, 0, 0, 0};

    __syncthreads();                           // LDS slot vectors ready

    if (w >= 4) {
        // ---- Pairwise waves: (j-half, i-half); 16 chunks of 32 i per tile ----
        const int jh_ = (w - 4) & 1;
        const int ih  = (w - 4) >> 1;
        const int j31 = l & 31;
        const f32x16 Z = {0.f,0.f,0.f,0.f,0.f,0.f,0.f,0.f,
                          0.f,0.f,0.f,0.f,0.f,0.f,0.f,0.f};
        for (int t = 0; t < 2; ++t) {
            const int jj = t * 64 + 32 * jh_ + j31;
            const bf16x8* bp = (l < 32) ? &jlo[jj] : &jhi[jj];
            bf16x8 Bj = *bp;
            float aw0 = 0.f, aw1 = 0.f, at0 = 0.f, at1 = 0.f;
            __builtin_amdgcn_s_setprio(1);
            #pragma unroll
            for (int c = 0; c < 16; ++c) {
                const bf16x8* ap = (l < 32)
                    ? (const bf16x8*)&ivec[(ih * 512 + c * 32 + j31) * 8]
                    : &cst;
                bf16x8 Af = *ap;
                f32x16 S = __builtin_amdgcn_mfma_f32_32x32x16_bf16(Af, Bj, Z, 0, 0, 0);
                #pragma unroll
                for (int r = 0; r < 16; r += 2) {
                    float p2a = S[r], p2b = S[r + 1];
                    float wa = __builtin_amdgcn_exp2f(p2a);
                    float wb = __builtin_amdgcn_exp2f(p2b);
                    aw0 += wa;                 aw1 += wb;
                    at0 = fmaf(p2a, wa, at0);  at1 = fmaf(p2b, wb, at1);
                }
            }
            __builtin_amdgcn_s_setprio(0);
            float aw = aw0 + aw1, at = at0 + at1;
            aw += __shfl_xor(aw, 32);          // combine lane-halves
            at += __shfl_xor(at, 32);
            if (l < 32) {
                part_w[t][ih][32 * jh_ + j31] = aw;
                part_t[t][ih][32 * jh_ + j31] = at;
            }
            __syncthreads();                   // partials for tile t ready
        }
    } else {
        // ---- GEMM waves: 32 cols x 64 rows per tile, hi-only bf16 dual-GEMM ----
        const int colbase = (w & 3) * 32;
        const f32x4 Z4 = {0.f, 0.f, 0.f, 0.f};
        f32x4 acc[4][2][2];                    // [msub][colgrp][gemm]

        bf16x8 Bh[2][2][2];                    // [colgrp][gemm][q] — built ONCE
        #pragma unroll
        for (int cg = 0; cg < 2; ++cg)
            #pragma unroll
            for (int g = 0; g < 2; ++g)
                #pragma unroll
                for (int q = 0; q < 2; ++q) {
                    const float* ap = A + (size_t)(g * FF + 32 * q + 8 * lh) * OO
                                      + colbase + 16 * cg + l16;
                    #pragma unroll
                    for (int e = 0; e < 8; ++e)
                        Bh[cg][g][q][e] = bfh(ap[(size_t)e * OO]);
                }
        float a2v[2], bbv[2];
        #pragma unroll
        for (int cg = 0; cg < 2; ++cg) {
            a2v[cg] = A[(size_t)(2 * FF) * OO + colbase + 16 * cg + l16];
            bbv[cg] = bias[colbase + 16 * cg + l16];
        }

        for (int t = 0; t < 2; ++t) {
            const float* xpb = x + (size_t)(rowbase_g + t * 64 + l16) * FF + 8 * lh;
            #pragma unroll
            for (int ms = 0; ms < 4; ++ms) {
                const float* _p = xpb + ms * 16 * FF;
                float4 v0 = *(const float4*)(_p);
                float4 v1 = *(const float4*)(_p + 4);
                float4 v2 = *(const float4*)(_p + 32);
                float4 v3 = *(const float4*)(_p + 36);
                float src[16] = {v0.x, v0.y, v0.z, v0.w, v1.x, v1.y, v1.z, v1.w,
                                 v2.x, v2.y, v2.z, v2.w, v3.x, v3.y, v3.z, v3.w};
                bf16x8 Xh[2];
                #pragma unroll
                for (int q = 0; q < 2; ++q)
                    #pragma unroll
                    for (int e = 0; e < 8; ++e)
                        Xh[q][e] = bfh(src[q * 8 + e]);
                #pragma unroll
                for (int cg = 0; cg < 2; ++cg)
                    #pragma unroll
                    for (int g = 0; g < 2; ++g) {
                        acc[ms][cg][g] = __builtin_amdgcn_mfma_f32_16x16x32_bf16(
                            Xh[0], Bh[cg][g][0], Z4, 0, 0, 0);
                        acc[ms][cg][g] = __builtin_amdgcn_mfma_f32_16x16x32_bf16(
                            Xh[1], Bh[cg][g][1], acc[ms][cg][g], 0, 0, 0);
                    }
            }

            __syncthreads();                   // partials for tile t ready

            // ---- Epilogue tile t: direct partial combine ----
            #pragma unroll
            for (int ms = 0; ms < 4; ++ms) {
                const int rl  = 16 * ms + 4 * lh;
                const int erg = rowbase_g + t * 64 + rl;
                float4 mk = *(const float4*)(mask + erg);
                float4 w0 = *(const float4*)&part_w[t][0][rl];
                float4 w1 = *(const float4*)&part_w[t][1][rl];
                float4 t0 = *(const float4*)&part_t[t][0][rl];
                float4 t1 = *(const float4*)&part_t[t][1][rl];
                float mks[4] = {mk.x, mk.y, mk.z, mk.w};
                float wvs[4] = {w0.x + w1.x, w0.y + w1.y, w0.z + w1.z, w0.w + w1.w};
                float dvs[4] = {(t0.x + t1.x) * NEG_LN2_10, (t0.y + t1.y) * NEG_LN2_10,
                                (t0.z + t1.z) * NEG_LN2_10, (t0.w + t1.w) * NEG_LN2_10};
                #pragma unroll
                for (int r = 0; r < 4; ++r) {
                    const int row = erg + r;
                    const float m   = mks[r];
                    const float s   = wvs[r] * m - 1.f;
                    const float dwm = dvs[r] * m;
                    #pragma unroll
                    for (int cg = 0; cg < 2; ++cg) {
                        float val = acc[ms][cg][0][r] + s * acc[ms][cg][1][r]
                                  + dwm * a2v[cg] + bbv[cg];
                        out[(size_t)row * OO + colbase + 16 * cg + l16] = val * m;
                    }
                }
            }
        }
    }
}

extern "C" void kernel_launch(void* const* d_in, const int* in_sizes, int n_in,
                              void* d_out, int out_size, void* d_ws, size_t ws_size,
                              hipStream_t stream)
{
    const float* x    = (const float*)d_in[0];
    const float* mask = (const float*)d_in[1];
    const float* A    = (const float*)d_in[2];
    const float* bias = (const float*)d_in[3];
    float* out = (float*)d_out;

    // DIAGNOSTIC: launch twice (idempotent). Marginal cost of the 2nd launch
    // = true kernel device time + in-graph gap.
    gnn_fused_kernel<<<dim3(256), dim3(512), 0, stream>>>(x, mask, A, bias, out);
    gnn_fused_kernel<<<dim3(256), dim3(512), 0, stream>>>(x, mask, A, bias, out);
}

// Round 7
// 22.485 us; speedup vs baseline: 1.1731x; 1.1731x over previous
//
#include <hip/hip_runtime.h>
#include <hip/hip_bf16.h>

typedef __attribute__((ext_vector_type(8))) short bf16x8;
typedef __attribute__((ext_vector_type(4))) float f32x4;
typedef __attribute__((ext_vector_type(16))) float f32x16;

#define NN 1024
#define FF 64
#define OO 128

#define LOG2E    1.4426950408889634f
#define C20L     (20.0f * LOG2E)
#define C10L     (10.0f * LOG2E)
#define NEG_LN2_10 (-0.06931471805599453f)
#define BF1      ((short)0x3F80)        // bf16 1.0

__device__ __forceinline__ short bfh(float f) {
    __hip_bfloat16 h = __float2bfloat16(f);   // RNE
    return *reinterpret_cast<short*>(&h);
}
__device__ __forceinline__ float bf2f(short s) {
    union { unsigned u; float f; } v; v.u = ((unsigned)(unsigned short)s) << 16;
    return v.f;
}

// ============================================================================
// R24: homogeneous phases (diagnostic R23 showed K=10.6us device, X=5.1us
// harness overhead -> ~5us recoverable).
// Theory: R18's wave specialization leaves ONE pairwise wave per SIMD after
// its GEMM partner parks (~1us in): all exp2 trans-pipe stalls (8cy each) and
// MFMA->exp dependencies are exposed -> pairwise phase 2.8us issue runs at
// ~5-6us. Fix: all 8 waves each do ONE pairwise unit (t,ih,jg) so each SIMD
// has TWO active pairwise waves (w, w+4) -> trans pipe saturated (128cy/chunk,
// VALU hidden), stalls mutually hidden. Then all 8 waves do 16-col GEMM +
// epilogue for both tiles (8-way store issue). Bh prep hoisted to kernel top
// (A-load latency drains under Phase A). No forced launch_bounds (R21 trap).
// Per-unit op sequence identical to R18 -> bitwise-same numerics.
// 256 blocks (32 batches x 8 j-tiles of 128 rows) x 512 threads.
// ============================================================================
__global__ __launch_bounds__(512) void gnn_fused_kernel(
    const float* __restrict__ x, const float* __restrict__ mask,
    const float* __restrict__ A, const float* __restrict__ bias,
    float* __restrict__ out)
{
    __shared__ __align__(16) short  ivec[NN * 8];        // 16 KB: i-side A-slots
    __shared__ __align__(16) bf16x8 jlo[128], jhi[128];  // 4 KB: j-side B-slots
    __shared__ __align__(16) bf16x8 cst;                 // A-slot for lanes>=32
    __shared__ __align__(16) float part_w[2][2][64];     // [tile][ih][j]
    __shared__ __align__(16) float part_t[2][2][64];

    const int tid = threadIdx.x;
    const int w   = tid >> 6;
    const int l   = tid & 63;
    const int l16 = l & 15;
    const int lh  = l >> 4;

    // XCD swizzle: all 8 j-tile blocks of a batch share one XCD (bid%8).
    const int bid = blockIdx.x;
    const int b     = (bid & 7) * 4 + (bid >> 6);
    const int jbase = ((bid >> 3) & 7) * 128;
    const int rowbase_g = b * NN + jbase;
    const float* xb = x + (size_t)b * NN * FF;

    // ---- Hoisted GEMM B-operand prep (every wave owns 16 cols) ----
    // Issued first so the strided A loads drain under Phase A.
    const int colbase = w * 16;
    bf16x8 Bh[2][2];                           // [gemm][q]
    #pragma unroll
    for (int g = 0; g < 2; ++g)
        #pragma unroll
        for (int q = 0; q < 2; ++q) {
            const float* ap = A + (size_t)(g * FF + 32 * q + 8 * lh) * OO
                              + colbase + l16;
            #pragma unroll
            for (int e = 0; e < 8; ++e)
                Bh[g][q][e] = bfh(ap[(size_t)e * OO]);
        }
    const float a2v = A[(size_t)(2 * FF) * OO + colbase + l16];
    const float bbv = bias[colbase + l16];

    // ---- Phase A (all waves): build split-bf16 slot vectors ----
    // p2[j][i] = vx_i*x_j + vy_i*y_j + u_i + u_j   (log2-domain, = -10L*dist)
    // A(i) k0..7: [vxh,vxl,vxh,vyh,vyl,vyh,uh,ul]  B(j) k0..7: [xh,xh,xl,yh,yh,yl,1,1]
    // lanes>=32 (k8..15): A=[1,1,0..]  B=[ujh,ujl,0..]
    #pragma unroll
    for (int q = 0; q < 2; ++q) {
        int p = tid + q * 512;
        float2 c2 = *(const float2*)(xb + (size_t)p * FF + (FF - 2));
        float vx = C20L * c2.x, vy = C20L * c2.y;
        float r2 = fmaf(c2.x, c2.x, c2.y * c2.y);
        float u  = -C10L * r2;
        short vxh = bfh(vx); short vxl = bfh(vx - bf2f(vxh));
        short vyh = bfh(vy); short vyl = bfh(vy - bf2f(vyh));
        short uh  = bfh(u);  short ul  = bfh(u  - bf2f(uh));
        bf16x8 iv = {vxh, vxl, vxh, vyh, vyl, vyh, uh, ul};
        *(bf16x8*)&ivec[p * 8] = iv;
        unsigned jloc = (unsigned)(p - jbase);
        if (jloc < 128u) {
            short xh = bfh(c2.x); short xl = bfh(c2.x - bf2f(xh));
            short yh = bfh(c2.y); short yl = bfh(c2.y - bf2f(yh));
            jlo[jloc] = (bf16x8){xh, xh, xl, yh, yh, yl, BF1, BF1};
            jhi[jloc] = (bf16x8){uh, ul, 0, 0, 0, 0, 0, 0};
        }
    }
    if (tid == 0) cst = (bf16x8){BF1, BF1, 0, 0, 0, 0, 0, 0};

    __syncthreads();                           // B1: LDS slot vectors ready

    // ---- P1: ONE pairwise unit per wave; 2 active pairwise waves/SIMD ----
    {
        const int t_  = w >> 2;                // tile
        const int ih  = (w >> 1) & 1;          // i-half (512 i)
        const int jg  = w & 1;                 // 32-j group within tile
        const int j31 = l & 31;
        const int jj = t_ * 64 + 32 * jg + j31;
        const bf16x8* bp = (l < 32) ? &jlo[jj] : &jhi[jj];
        bf16x8 Bj = *bp;
        const f32x16 Z = {0.f,0.f,0.f,0.f,0.f,0.f,0.f,0.f,
                          0.f,0.f,0.f,0.f,0.f,0.f,0.f,0.f};
        float aw0 = 0.f, aw1 = 0.f, at0 = 0.f, at1 = 0.f;
        __builtin_amdgcn_s_setprio(1);
        #pragma unroll
        for (int c = 0; c < 16; ++c) {
            const bf16x8* ap = (l < 32)
                ? (const bf16x8*)&ivec[(ih * 512 + c * 32 + j31) * 8]
                : &cst;
            bf16x8 Af = *ap;
            f32x16 S = __builtin_amdgcn_mfma_f32_32x32x16_bf16(Af, Bj, Z, 0, 0, 0);
            #pragma unroll
            for (int r = 0; r < 16; r += 2) {
                float p2a = S[r], p2b = S[r + 1];
                float wa = __builtin_amdgcn_exp2f(p2a);
                float wb = __builtin_amdgcn_exp2f(p2b);
                aw0 += wa;                 aw1 += wb;
                at0 = fmaf(p2a, wa, at0);  at1 = fmaf(p2b, wb, at1);
            }
        }
        __builtin_amdgcn_s_setprio(0);
        float aw = aw0 + aw1, at = at0 + at1;
        aw += __shfl_xor(aw, 32);              // combine lane-halves
        at += __shfl_xor(at, 32);
        if (l < 32) {
            part_w[t_][ih][32 * jg + j31] = aw;
            part_t[t_][ih][32 * jg + j31] = at;
        }
    }

    __syncthreads();                           // B2: ALL partials ready

    // ---- P2: all 8 waves: 16-col dual-GEMM + epilogue, both tiles ----
    const f32x4 Z4 = {0.f, 0.f, 0.f, 0.f};
    for (int t = 0; t < 2; ++t) {
        f32x4 acc[4][2];                       // [msub][gemm]
        const float* xpb = x + (size_t)(rowbase_g + t * 64 + l16) * FF + 8 * lh;
        #pragma unroll
        for (int ms = 0; ms < 4; ++ms) {
            const float* _p = xpb + ms * 16 * FF;
            float4 v0 = *(const float4*)(_p);
            float4 v1 = *(const float4*)(_p + 4);
            float4 v2 = *(const float4*)(_p + 32);
            float4 v3 = *(const float4*)(_p + 36);
            float src[16] = {v0.x, v0.y, v0.z, v0.w, v1.x, v1.y, v1.z, v1.w,
                             v2.x, v2.y, v2.z, v2.w, v3.x, v3.y, v3.z, v3.w};
            bf16x8 Xh[2];
            #pragma unroll
            for (int q = 0; q < 2; ++q)
                #pragma unroll
                for (int e = 0; e < 8; ++e)
                    Xh[q][e] = bfh(src[q * 8 + e]);
            #pragma unroll
            for (int g = 0; g < 2; ++g) {
                acc[ms][g] = __builtin_amdgcn_mfma_f32_16x16x32_bf16(
                    Xh[0], Bh[g][0], Z4, 0, 0, 0);
                acc[ms][g] = __builtin_amdgcn_mfma_f32_16x16x32_bf16(
                    Xh[1], Bh[g][1], acc[ms][g], 0, 0, 0);
            }
        }

        // ---- Epilogue tile t: direct partial combine, stores 8-wave wide ----
        #pragma unroll
        for (int ms = 0; ms < 4; ++ms) {
            const int rl  = 16 * ms + 4 * lh;
            const int erg = rowbase_g + t * 64 + rl;
            float4 mk = *(const float4*)(mask + erg);
            float4 w0 = *(const float4*)&part_w[t][0][rl];
            float4 w1 = *(const float4*)&part_w[t][1][rl];
            float4 t0 = *(const float4*)&part_t[t][0][rl];
            float4 t1 = *(const float4*)&part_t[t][1][rl];
            float mks[4] = {mk.x, mk.y, mk.z, mk.w};
            float wvs[4] = {w0.x + w1.x, w0.y + w1.y, w0.z + w1.z, w0.w + w1.w};
            float dvs[4] = {(t0.x + t1.x) * NEG_LN2_10, (t0.y + t1.y) * NEG_LN2_10,
                            (t0.z + t1.z) * NEG_LN2_10, (t0.w + t1.w) * NEG_LN2_10};
            #pragma unroll
            for (int r = 0; r < 4; ++r) {
                const int row = erg + r;
                const float m   = mks[r];
                const float s   = wvs[r] * m - 1.f;
                const float dwm = dvs[r] * m;
                float val = acc[ms][0][r] + s * acc[ms][1][r]
                          + dwm * a2v + bbv;
                out[(size_t)row * OO + colbase + l16] = val * m;
            }
        }
    }
}

extern "C" void kernel_launch(void* const* d_in, const int* in_sizes, int n_in,
                              void* d_out, int out_size, void* d_ws, size_t ws_size,
                              hipStream_t stream)
{
    const float* x    = (const float*)d_in[0];
    const float* mask = (const float*)d_in[1];
    const float* A    = (const float*)d_in[2];
    const float* bias = (const float*)d_in[3];
    float* out = (float*)d_out;

    gnn_fused_kernel<<<dim3(256), dim3(512), 0, stream>>>(x, mask, A, bias, out);
}

// Round 8
// 16.868 us; speedup vs baseline: 1.5636x; 1.3329x over previous
//
#include <hip/hip_runtime.h>
#include <hip/hip_bf16.h>

typedef __attribute__((ext_vector_type(8))) short bf16x8;
typedef __attribute__((ext_vector_type(4))) float f32x4;
typedef __attribute__((ext_vector_type(16))) float f32x16;

#define NN 1024
#define FF 64
#define OO 128

#define LOG2E    1.4426950408889634f
#define C20L     (20.0f * LOG2E)
#define C10L     (10.0f * LOG2E)
#define NEG_LN2_10 (-0.06931471805599453f)
#define BF1      ((short)0x3F80)        // bf16 1.0

__device__ __forceinline__ short bfh(float f) {
    __hip_bfloat16 h = __float2bfloat16(f);   // RNE
    return *reinterpret_cast<short*>(&h);
}
__device__ __forceinline__ float bf2f(short s) {
    union { unsigned u; float f; } v; v.u = ((unsigned)(unsigned short)s) << 16;
    return v.f;
}

// ============================================================================
// R25 = R18 (best measured: 15.74us; wave-specialized, concurrent GEMM) + two
// surgical, mechanism-backed changes. 7-round evidence: every sequential-phase
// restructure lost ~6us vs wave-specialized; R23 diagnostic: device K=10.6us,
// fixed harness overhead X=5.1us.
//  S1: column-interleaved dual fragments (col = colbase + 2*l16 + cg) ->
//      epilogue stores float2/lane: 4x128B full lines per step instead of
//      64B half-lines; halves store instruction count. Numerics identical.
//  S2: tile-1 x rows prefetched+cvt'd to bf16 (32 VGPR) BEFORE the tile-0
//      partials barrier: the 16 global loads retire during the barrier wait
//      (GEMM waves previously parked idle, then loaded cold after epilogue).
//      Peak VGPR ~190 < 256 -> occupancy unchanged (2 waves/SIMD).
// 256 blocks (32 batches x 8 j-tiles of 128 rows) x 512 threads (8 waves).
// ============================================================================
__global__ __launch_bounds__(512) void gnn_fused_kernel(
    const float* __restrict__ x, const float* __restrict__ mask,
    const float* __restrict__ A, const float* __restrict__ bias,
    float* __restrict__ out)
{
    __shared__ __align__(16) short  ivec[NN * 8];        // 16 KB: i-side A-slots
    __shared__ __align__(16) bf16x8 jlo[128], jhi[128];  // 4 KB: j-side B-slots
    __shared__ __align__(16) bf16x8 cst;                 // A-slot for lanes>=32
    __shared__ __align__(16) float part_w[2][2][64];     // [tile][ih][j]
    __shared__ __align__(16) float part_t[2][2][64];

    const int tid = threadIdx.x;
    const int w   = tid >> 6;
    const int l   = tid & 63;
    const int l16 = l & 15;
    const int lh  = l >> 4;

    // XCD swizzle: all 8 j-tile blocks of a batch share one XCD (bid%8).
    const int bid = blockIdx.x;
    const int b     = (bid & 7) * 4 + (bid >> 6);
    const int jbase = ((bid >> 3) & 7) * 128;
    const int rowbase_g = b * NN + jbase;
    const float* xb = x + (size_t)b * NN * FF;

    // ---- Phase A (all waves): build split-bf16 slot vectors ----
    // p2[j][i] = vx_i*x_j + vy_i*y_j + u_i + u_j   (log2-domain, = -10L*dist)
    // A(i) k0..7: [vxh,vxl,vxh,vyh,vyl,vyh,uh,ul]  B(j) k0..7: [xh,xh,xl,yh,yh,yl,1,1]
    // lanes>=32 (k8..15): A=[1,1,0..]  B=[ujh,ujl,0..]
    #pragma unroll
    for (int q = 0; q < 2; ++q) {
        int p = tid + q * 512;
        float2 c2 = *(const float2*)(xb + (size_t)p * FF + (FF - 2));
        float vx = C20L * c2.x, vy = C20L * c2.y;
        float r2 = fmaf(c2.x, c2.x, c2.y * c2.y);
        float u  = -C10L * r2;
        short vxh = bfh(vx); short vxl = bfh(vx - bf2f(vxh));
        short vyh = bfh(vy); short vyl = bfh(vy - bf2f(vyh));
        short uh  = bfh(u);  short ul  = bfh(u  - bf2f(uh));
        bf16x8 iv = {vxh, vxl, vxh, vyh, vyl, vyh, uh, ul};
        *(bf16x8*)&ivec[p * 8] = iv;
        unsigned jloc = (unsigned)(p - jbase);
        if (jloc < 128u) {
            short xh = bfh(c2.x); short xl = bfh(c2.x - bf2f(xh));
            short yh = bfh(c2.y); short yl = bfh(c2.y - bf2f(yh));
            jlo[jloc] = (bf16x8){xh, xh, xl, yh, yh, yl, BF1, BF1};
            jhi[jloc] = (bf16x8){uh, ul, 0, 0, 0, 0, 0, 0};
        }
    }
    if (tid == 0) cst = (bf16x8){BF1, BF1, 0, 0, 0, 0, 0, 0};

    __syncthreads();                           // LDS slot vectors ready

    if (w >= 4) {
        // ---- Pairwise waves (UNCHANGED from R18): (j-half, i-half) ----
        const int jh_ = (w - 4) & 1;
        const int ih  = (w - 4) >> 1;
        const int j31 = l & 31;
        const f32x16 Z = {0.f,0.f,0.f,0.f,0.f,0.f,0.f,0.f,
                          0.f,0.f,0.f,0.f,0.f,0.f,0.f,0.f};
        for (int t = 0; t < 2; ++t) {
            const int jj = t * 64 + 32 * jh_ + j31;
            const bf16x8* bp = (l < 32) ? &jlo[jj] : &jhi[jj];
            bf16x8 Bj = *bp;
            float aw0 = 0.f, aw1 = 0.f, at0 = 0.f, at1 = 0.f;
            __builtin_amdgcn_s_setprio(1);
            #pragma unroll
            for (int c = 0; c < 16; ++c) {
                const bf16x8* ap = (l < 32)
                    ? (const bf16x8*)&ivec[(ih * 512 + c * 32 + j31) * 8]
                    : &cst;
                bf16x8 Af = *ap;
                f32x16 S = __builtin_amdgcn_mfma_f32_32x32x16_bf16(Af, Bj, Z, 0, 0, 0);
                #pragma unroll
                for (int r = 0; r < 16; r += 2) {
                    float p2a = S[r], p2b = S[r + 1];
                    float wa = __builtin_amdgcn_exp2f(p2a);
                    float wb = __builtin_amdgcn_exp2f(p2b);
                    aw0 += wa;                 aw1 += wb;
                    at0 = fmaf(p2a, wa, at0);  at1 = fmaf(p2b, wb, at1);
                }
            }
            __builtin_amdgcn_s_setprio(0);
            float aw = aw0 + aw1, at = at0 + at1;
            aw += __shfl_xor(aw, 32);          // combine lane-halves
            at += __shfl_xor(at, 32);
            if (l < 32) {
                part_w[t][ih][32 * jh_ + j31] = aw;
                part_t[t][ih][32 * jh_ + j31] = at;
            }
            __syncthreads();                   // partials for tile t ready
        }
    } else {
        // ---- GEMM waves: 32 cols x 64 rows per tile, interleaved fragments ----
        // S1: fragment cg holds cols colbase + 2*l16 + cg  -> float2 stores.
        const int colbase = (w & 3) * 32;
        const int c2i = colbase + 2 * l16;
        const f32x4 Z4 = {0.f, 0.f, 0.f, 0.f};
        f32x4 acc[4][2][2];                    // [msub][cg][gemm]

        bf16x8 Bh[2][2][2];                    // [cg][gemm][q] — built ONCE
        #pragma unroll
        for (int cg = 0; cg < 2; ++cg)
            #pragma unroll
            for (int g = 0; g < 2; ++g)
                #pragma unroll
                for (int q = 0; q < 2; ++q) {
                    const float* ap = A + (size_t)(g * FF + 32 * q + 8 * lh) * OO
                                      + c2i + cg;
                    #pragma unroll
                    for (int e = 0; e < 8; ++e)
                        Bh[cg][g][q][e] = bfh(ap[(size_t)e * OO]);
                }
        float a2v[2], bbv[2];
        #pragma unroll
        for (int cg = 0; cg < 2; ++cg) {
            a2v[cg] = A[(size_t)(2 * FF) * OO + c2i + cg];
            bbv[cg] = bias[c2i + cg];
        }

        // ---- tile 0: load + cvt + MFMA ----
        {
            const float* xpb = x + (size_t)(rowbase_g + l16) * FF + 8 * lh;
            #pragma unroll
            for (int ms = 0; ms < 4; ++ms) {
                const float* _p = xpb + ms * 16 * FF;
                float4 v0 = *(const float4*)(_p);
                float4 v1 = *(const float4*)(_p + 4);
                float4 v2 = *(const float4*)(_p + 32);
                float4 v3 = *(const float4*)(_p + 36);
                float src[16] = {v0.x, v0.y, v0.z, v0.w, v1.x, v1.y, v1.z, v1.w,
                                 v2.x, v2.y, v2.z, v2.w, v3.x, v3.y, v3.z, v3.w};
                bf16x8 Xh[2];
                #pragma unroll
                for (int q = 0; q < 2; ++q)
                    #pragma unroll
                    for (int e = 0; e < 8; ++e)
                        Xh[q][e] = bfh(src[q * 8 + e]);
                #pragma unroll
                for (int cg = 0; cg < 2; ++cg)
                    #pragma unroll
                    for (int g = 0; g < 2; ++g) {
                        acc[ms][cg][g] = __builtin_amdgcn_mfma_f32_16x16x32_bf16(
                            Xh[0], Bh[cg][g][0], Z4, 0, 0, 0);
                        acc[ms][cg][g] = __builtin_amdgcn_mfma_f32_16x16x32_bf16(
                            Xh[1], Bh[cg][g][1], acc[ms][cg][g], 0, 0, 0);
                    }
            }
        }

        // ---- S2: prefetch + cvt tile-1 X BEFORE waiting on tile-0 partials ----
        bf16x8 Xn[4][2];
        {
            const float* xpb = x + (size_t)(rowbase_g + 64 + l16) * FF + 8 * lh;
            #pragma unroll
            for (int ms = 0; ms < 4; ++ms) {
                const float* _p = xpb + ms * 16 * FF;
                float4 v0 = *(const float4*)(_p);
                float4 v1 = *(const float4*)(_p + 4);
                float4 v2 = *(const float4*)(_p + 32);
                float4 v3 = *(const float4*)(_p + 36);
                float src[16] = {v0.x, v0.y, v0.z, v0.w, v1.x, v1.y, v1.z, v1.w,
                                 v2.x, v2.y, v2.z, v2.w, v3.x, v3.y, v3.z, v3.w};
                #pragma unroll
                for (int q = 0; q < 2; ++q)
                    #pragma unroll
                    for (int e = 0; e < 8; ++e)
                        Xn[ms][q][e] = bfh(src[q * 8 + e]);
            }
        }

        __syncthreads();                       // tile-0 partials ready

        // ---- Epilogue tile 0 (float2 full-line stores) ----
        #pragma unroll
        for (int ms = 0; ms < 4; ++ms) {
            const int rl  = 16 * ms + 4 * lh;
            const int erg = rowbase_g + rl;
            float4 mk = *(const float4*)(mask + erg);
            float4 w0 = *(const float4*)&part_w[0][0][rl];
            float4 w1 = *(const float4*)&part_w[0][1][rl];
            float4 t0 = *(const float4*)&part_t[0][0][rl];
            float4 t1 = *(const float4*)&part_t[0][1][rl];
            float mks[4] = {mk.x, mk.y, mk.z, mk.w};
            float wvs[4] = {w0.x + w1.x, w0.y + w1.y, w0.z + w1.z, w0.w + w1.w};
            float dvs[4] = {(t0.x + t1.x) * NEG_LN2_10, (t0.y + t1.y) * NEG_LN2_10,
                            (t0.z + t1.z) * NEG_LN2_10, (t0.w + t1.w) * NEG_LN2_10};
            #pragma unroll
            for (int r = 0; r < 4; ++r) {
                const int row = erg + r;
                const float m   = mks[r];
                const float s   = wvs[r] * m - 1.f;
                const float dwm = dvs[r] * m;
                float2 st;
                st.x = (acc[ms][0][0][r] + s * acc[ms][0][1][r]
                        + dwm * a2v[0] + bbv[0]) * m;
                st.y = (acc[ms][1][0][r] + s * acc[ms][1][1][r]
                        + dwm * a2v[1] + bbv[1]) * m;
                *(float2*)(out + (size_t)row * OO + c2i) = st;
            }
        }

        // ---- tile 1 MFMA from prefetched Xn ----
        #pragma unroll
        for (int ms = 0; ms < 4; ++ms)
            #pragma unroll
            for (int cg = 0; cg < 2; ++cg)
                #pragma unroll
                for (int g = 0; g < 2; ++g) {
                    acc[ms][cg][g] = __builtin_amdgcn_mfma_f32_16x16x32_bf16(
                        Xn[ms][0], Bh[cg][g][0], Z4, 0, 0, 0);
                    acc[ms][cg][g] = __builtin_amdgcn_mfma_f32_16x16x32_bf16(
                        Xn[ms][1], Bh[cg][g][1], acc[ms][cg][g], 0, 0, 0);
                }

        __syncthreads();                       // tile-1 partials ready

        // ---- Epilogue tile 1 ----
        #pragma unroll
        for (int ms = 0; ms < 4; ++ms) {
            const int rl  = 16 * ms + 4 * lh;
            const int erg = rowbase_g + 64 + rl;
            float4 mk = *(const float4*)(mask + erg);
            float4 w0 = *(const float4*)&part_w[1][0][rl];
            float4 w1 = *(const float4*)&part_w[1][1][rl];
            float4 t0 = *(const float4*)&part_t[1][0][rl];
            float4 t1 = *(const float4*)&part_t[1][1][rl];
            float mks[4] = {mk.x, mk.y, mk.z, mk.w};
            float wvs[4] = {w0.x + w1.x, w0.y + w1.y, w0.z + w1.z, w0.w + w1.w};
            float dvs[4] = {(t0.x + t1.x) * NEG_LN2_10, (t0.y + t1.y) * NEG_LN2_10,
                            (t0.z + t1.z) * NEG_LN2_10, (t0.w + t1.w) * NEG_LN2_10};
            #pragma unroll
            for (int r = 0; r < 4; ++r) {
                const int row = erg + r;
                const float m   = mks[r];
                const float s   = wvs[r] * m - 1.f;
                const float dwm = dvs[r] * m;
                float2 st;
                st.x = (acc[ms][0][0][r] + s * acc[ms][0][1][r]
                        + dwm * a2v[0] + bbv[0]) * m;
                st.y = (acc[ms][1][0][r] + s * acc[ms][1][1][r]
                        + dwm * a2v[1] + bbv[1]) * m;
                *(float2*)(out + (size_t)row * OO + c2i) = st;
            }
        }
    }
}

extern "C" void kernel_launch(void* const* d_in, const int* in_sizes, int n_in,
                              void* d_out, int out_size, void* d_ws, size_t ws_size,
                              hipStream_t stream)
{
    const float* x    = (const float*)d_in[0];
    const float* mask = (const float*)d_in[1];
    const float* A    = (const float*)d_in[2];
    const float* bias = (const float*)d_in[3];
    float* out = (float*)d_out;

    gnn_fused_kernel<<<dim3(256), dim3(512), 0, stream>>>(x, mask, A, bias, out);
}

// Round 9
// 15.605 us; speedup vs baseline: 1.6903x; 1.0810x over previous
//
#include <hip/hip_runtime.h>
#include <hip/hip_bf16.h>

typedef __attribute__((ext_vector_type(8))) short bf16x8;
typedef __attribute__((ext_vector_type(4))) float f32x4;
typedef __attribute__((ext_vector_type(16))) float f32x16;

#define NN 1024
#define FF 64
#define OO 128

#define LOG2E    1.4426950408889634f
#define C20L     (20.0f * LOG2E)
#define C10L     (10.0f * LOG2E)
#define NEG_LN2_10 (-0.06931471805599453f)
#define BF1      ((short)0x3F80)        // bf16 1.0

__device__ __forceinline__ short bfh(float f) {
    __hip_bfloat16 h = __float2bfloat16(f);   // RNE
    return *reinterpret_cast<short*>(&h);
}
__device__ __forceinline__ float bf2f(short s) {
    union { unsigned u; float f; } v; v.u = ((unsigned)(unsigned short)s) << 16;
    return v.f;
}

// ============================================================================
// R26 = R18 restored verbatim (best of 9 measured variants: 15.74us).
// Session close-out. Evidence: dur_us = ~5.1us fixed harness overhead +
// ~10.6us device (R23 double-launch diagnostic). Structural alternatives
// (sequential phases R21/R24, 2-kernel split R20, forced occupancy R19) all
// lost 0.5-6us to this wave-specialized concurrent shape; surgical changes
// within it (SW pipeline R22, full-line stores + prefetch R25) measured
// neutral-to-negative. Conclusion: practical floor for this problem size on
// MI355X (N=1024: too small to fill 256 CUs with deep per-SIMD wave cover).
// 256 blocks (32 batches x 8 j-tiles of 128 rows), 512 threads (8 waves).
// Waves 4-7: pairwise exp phase. Waves 0-3: dual-GEMM + epilogue.
// ============================================================================
__global__ __launch_bounds__(512) void gnn_fused_kernel(
    const float* __restrict__ x, const float* __restrict__ mask,
    const float* __restrict__ A, const float* __restrict__ bias,
    float* __restrict__ out)
{
    __shared__ __align__(16) short  ivec[NN * 8];        // 16 KB: i-side A-slots
    __shared__ __align__(16) bf16x8 jlo[128], jhi[128];  // 4 KB: j-side B-slots
    __shared__ __align__(16) bf16x8 cst;                 // A-slot for lanes>=32
    __shared__ __align__(16) float part_w[2][2][64];     // [tile][ih][j]
    __shared__ __align__(16) float part_t[2][2][64];

    const int tid = threadIdx.x;
    const int w   = tid >> 6;
    const int l   = tid & 63;
    const int l16 = l & 15;
    const int lh  = l >> 4;

    // XCD swizzle: all 8 j-tile blocks of a batch share one XCD (bid%8).
    const int bid = blockIdx.x;
    const int b     = (bid & 7) * 4 + (bid >> 6);
    const int jbase = ((bid >> 3) & 7) * 128;
    const int rowbase_g = b * NN + jbase;
    const float* xb = x + (size_t)b * NN * FF;

    // ---- Phase A (all waves): build split-bf16 slot vectors ----
    // p2[j][i] = vx_i*x_j + vy_i*y_j + u_i + u_j   (log2-domain, = -10L*dist)
    // A(i) k0..7: [vxh,vxl,vxh,vyh,vyl,vyh,uh,ul]  B(j) k0..7: [xh,xh,xl,yh,yh,yl,1,1]
    // lanes>=32 (k8..15): A=[1,1,0..]  B=[ujh,ujl,0..]
    #pragma unroll
    for (int q = 0; q < 2; ++q) {
        int p = tid + q * 512;
        float2 c2 = *(const float2*)(xb + (size_t)p * FF + (FF - 2));
        float vx = C20L * c2.x, vy = C20L * c2.y;
        float r2 = fmaf(c2.x, c2.x, c2.y * c2.y);
        float u  = -C10L * r2;
        short vxh = bfh(vx); short vxl = bfh(vx - bf2f(vxh));
        short vyh = bfh(vy); short vyl = bfh(vy - bf2f(vyh));
        short uh  = bfh(u);  short ul  = bfh(u  - bf2f(uh));
        bf16x8 iv = {vxh, vxl, vxh, vyh, vyl, vyh, uh, ul};
        *(bf16x8*)&ivec[p * 8] = iv;
        unsigned jloc = (unsigned)(p - jbase);
        if (jloc < 128u) {
            short xh = bfh(c2.x); short xl = bfh(c2.x - bf2f(xh));
            short yh = bfh(c2.y); short yl = bfh(c2.y - bf2f(yh));
            jlo[jloc] = (bf16x8){xh, xh, xl, yh, yh, yl, BF1, BF1};
            jhi[jloc] = (bf16x8){uh, ul, 0, 0, 0, 0, 0, 0};
        }
    }
    if (tid == 0) cst = (bf16x8){BF1, BF1, 0, 0, 0, 0, 0, 0};

    __syncthreads();                           // LDS slot vectors ready

    if (w >= 4) {
        // ---- Pairwise waves: (j-half, i-half); 16 chunks of 32 i per tile ----
        const int jh_ = (w - 4) & 1;
        const int ih  = (w - 4) >> 1;
        const int j31 = l & 31;
        const f32x16 Z = {0.f,0.f,0.f,0.f,0.f,0.f,0.f,0.f,
                          0.f,0.f,0.f,0.f,0.f,0.f,0.f,0.f};
        for (int t = 0; t < 2; ++t) {
            const int jj = t * 64 + 32 * jh_ + j31;
            const bf16x8* bp = (l < 32) ? &jlo[jj] : &jhi[jj];
            bf16x8 Bj = *bp;
            float aw0 = 0.f, aw1 = 0.f, at0 = 0.f, at1 = 0.f;
            __builtin_amdgcn_s_setprio(1);
            #pragma unroll
            for (int c = 0; c < 16; ++c) {
                const bf16x8* ap = (l < 32)
                    ? (const bf16x8*)&ivec[(ih * 512 + c * 32 + j31) * 8]
                    : &cst;
                bf16x8 Af = *ap;
                f32x16 S = __builtin_amdgcn_mfma_f32_32x32x16_bf16(Af, Bj, Z, 0, 0, 0);
                #pragma unroll
                for (int r = 0; r < 16; r += 2) {
                    float p2a = S[r], p2b = S[r + 1];
                    float wa = __builtin_amdgcn_exp2f(p2a);
                    float wb = __builtin_amdgcn_exp2f(p2b);
                    aw0 += wa;                 aw1 += wb;
                    at0 = fmaf(p2a, wa, at0);  at1 = fmaf(p2b, wb, at1);
                }
            }
            __builtin_amdgcn_s_setprio(0);
            float aw = aw0 + aw1, at = at0 + at1;
            aw += __shfl_xor(aw, 32);          // combine lane-halves
            at += __shfl_xor(at, 32);
            if (l < 32) {
                part_w[t][ih][32 * jh_ + j31] = aw;
                part_t[t][ih][32 * jh_ + j31] = at;
            }
            __syncthreads();                   // partials for tile t ready
        }
    } else {
        // ---- GEMM waves: 32 cols x 64 rows per tile, hi-only bf16 dual-GEMM ----
        const int colbase = (w & 3) * 32;
        const f32x4 Z4 = {0.f, 0.f, 0.f, 0.f};
        f32x4 acc[4][2][2];                    // [msub][colgrp][gemm]

        bf16x8 Bh[2][2][2];                    // [colgrp][gemm][q] — built ONCE
        #pragma unroll
        for (int cg = 0; cg < 2; ++cg)
            #pragma unroll
            for (int g = 0; g < 2; ++g)
                #pragma unroll
                for (int q = 0; q < 2; ++q) {
                    const float* ap = A + (size_t)(g * FF + 32 * q + 8 * lh) * OO
                                      + colbase + 16 * cg + l16;
                    #pragma unroll
                    for (int e = 0; e < 8; ++e)
                        Bh[cg][g][q][e] = bfh(ap[(size_t)e * OO]);
                }
        float a2v[2], bbv[2];
        #pragma unroll
        for (int cg = 0; cg < 2; ++cg) {
            a2v[cg] = A[(size_t)(2 * FF) * OO + colbase + 16 * cg + l16];
            bbv[cg] = bias[colbase + 16 * cg + l16];
        }

        for (int t = 0; t < 2; ++t) {
            const float* xpb = x + (size_t)(rowbase_g + t * 64 + l16) * FF + 8 * lh;
            #pragma unroll
            for (int ms = 0; ms < 4; ++ms) {
                const float* _p = xpb + ms * 16 * FF;
                float4 v0 = *(const float4*)(_p);
                float4 v1 = *(const float4*)(_p + 4);
                float4 v2 = *(const float4*)(_p + 32);
                float4 v3 = *(const float4*)(_p + 36);
                float src[16] = {v0.x, v0.y, v0.z, v0.w, v1.x, v1.y, v1.z, v1.w,
                                 v2.x, v2.y, v2.z, v2.w, v3.x, v3.y, v3.z, v3.w};
                bf16x8 Xh[2];
                #pragma unroll
                for (int q = 0; q < 2; ++q)
                    #pragma unroll
                    for (int e = 0; e < 8; ++e)
                        Xh[q][e] = bfh(src[q * 8 + e]);
                #pragma unroll
                for (int cg = 0; cg < 2; ++cg)
                    #pragma unroll
                    for (int g = 0; g < 2; ++g) {
                        acc[ms][cg][g] = __builtin_amdgcn_mfma_f32_16x16x32_bf16(
                            Xh[0], Bh[cg][g][0], Z4, 0, 0, 0);
                        acc[ms][cg][g] = __builtin_amdgcn_mfma_f32_16x16x32_bf16(
                            Xh[1], Bh[cg][g][1], acc[ms][cg][g], 0, 0, 0);
                    }
            }

            __syncthreads();                   // partials for tile t ready

            // ---- Epilogue tile t: direct partial combine ----
            #pragma unroll
            for (int ms = 0; ms < 4; ++ms) {
                const int rl  = 16 * ms + 4 * lh;
                const int erg = rowbase_g + t * 64 + rl;
                float4 mk = *(const float4*)(mask + erg);
                float4 w0 = *(const float4*)&part_w[t][0][rl];
                float4 w1 = *(const float4*)&part_w[t][1][rl];
                float4 t0 = *(const float4*)&part_t[t][0][rl];
                float4 t1 = *(const float4*)&part_t[t][1][rl];
                float mks[4] = {mk.x, mk.y, mk.z, mk.w};
                float wvs[4] = {w0.x + w1.x, w0.y + w1.y, w0.z + w1.z, w0.w + w1.w};
                float dvs[4] = {(t0.x + t1.x) * NEG_LN2_10, (t0.y + t1.y) * NEG_LN2_10,
                                (t0.z + t1.z) * NEG_LN2_10, (t0.w + t1.w) * NEG_LN2_10};
                #pragma unroll
                for (int r = 0; r < 4; ++r) {
                    const int row = erg + r;
                    const float m   = mks[r];
                    const float s   = wvs[r] * m - 1.f;
                    const float dwm = dvs[r] * m;
                    #pragma unroll
                    for (int cg = 0; cg < 2; ++cg) {
                        float val = acc[ms][cg][0][r] + s * acc[ms][cg][1][r]
                                  + dwm * a2v[cg] + bbv[cg];
                        out[(size_t)row * OO + colbase + 16 * cg + l16] = val * m;
                    }
                }
            }
        }
    }
}

extern "C" void kernel_launch(void* const* d_in, const int* in_sizes, int n_in,
                              void* d_out, int out_size, void* d_ws, size_t ws_size,
                              hipStream_t stream)
{
    const float* x    = (const float*)d_in[0];
    const float* mask = (const float*)d_in[1];
    const float* A    = (const float*)d_in[2];
    const float* bias = (const float*)d_in[3];
    float* out = (float*)d_out;

    gnn_fused_kernel<<<dim3(256), dim3(512), 0, stream>>>(x, mask, A, bias, out);
}